// Round 3
// baseline (165.412 us; speedup 1.0000x reference)
//
#include <hip/hip_runtime.h>
#include <hip/hip_bf16.h>
#include <math.h>

#define LSEQ 2048
#define DMODEL 256
#define NH 8
#define HD 32

typedef __attribute__((ext_vector_type(8))) short bf16x8;
typedef __attribute__((ext_vector_type(4))) float f32x4;

#define MFMA __builtin_amdgcn_mfma_f32_16x16x32_bf16

__device__ __forceinline__ short f2bf(float x) {
  __hip_bfloat16 h = __float2bfloat16(x);
  return __builtin_bit_cast(short, h);
}
__device__ __forceinline__ float bf2f(short s) {
  __hip_bfloat16 h = __builtin_bit_cast(__hip_bfloat16, s);
  return __bfloat162float(h);
}
__device__ __forceinline__ short bftrunc(float x) {      // truncating f32->bf16
  return (short)(__builtin_bit_cast(unsigned int, x) >> 16);
}
// bare v_exp_f32 (2^x) — skip OCML denormal fixup (underflowed p contribute 0)
__device__ __forceinline__ float fexp2(float x) {
#if __has_builtin(__builtin_amdgcn_exp2f)
  return __builtin_amdgcn_exp2f(x);
#else
  return __expf(x * 0.6931471805599453f);
#endif
}

// ---- aux: x -> bf16, Wqkv -> bf16, Wo -> split bf16, prior tables ----
__global__ __launch_bounds__(256) void aux_kernel(
    const float* __restrict__ x,
    const float* __restrict__ Wq, const float* __restrict__ Wk,
    const float* __restrict__ Wv, const float* __restrict__ Wo,
    const float* __restrict__ u,
    short* __restrict__ xh,
    short* __restrict__ Wh,
    short* __restrict__ Woh, short* __restrict__ Wol,
    float* __restrict__ Eb, float* __restrict__ Zb)
{
  __shared__ float Cs[LSEQ];
  __shared__ float part[256];
  const int tid = threadIdx.x;
  if (blockIdx.x < 1024) {            // x (4096x256 fp32) -> bf16, RNE
    const int i4 = (blockIdx.x * 256 + tid) * 4;
    float4 v = *(const float4*)(x + i4);
    *(short4*)(xh + i4) = make_short4(f2bf(v.x), f2bf(v.y), f2bf(v.z), f2bf(v.w));
    return;
  }
  const int bx = blockIdx.x - 1024;
  if (bx < 256) {
    const int i4 = (bx * 256 + tid) * 4;
    if (i4 < 196608) {
      int row = i4 >> 8, col = i4 & 255;
      const float* W = (row < 256) ? Wq : (row < 512) ? Wk : Wv;
      float4 v = *(const float4*)(W + (row & 255) * 256 + col);
      *(short4*)(Wh + i4) = make_short4(f2bf(v.x), f2bf(v.y), f2bf(v.z), f2bf(v.w));
    } else {
      int j = i4 - 196608;
      float4 v = *(const float4*)(Wo + j);
      short h0 = f2bf(v.x), h1 = f2bf(v.y), h2 = f2bf(v.z), h3 = f2bf(v.w);
      *(short4*)(Woh + j) = make_short4(h0, h1, h2, h3);
      *(short4*)(Wol + j) = make_short4(bftrunc(v.x - bf2f(h0)), bftrunc(v.y - bf2f(h1)),
                                        bftrunc(v.z - bf2f(h2)), bftrunc(v.w - bf2f(h3)));
    }
    return;
  }
  const int h = bx - 256;
  const float uu = u[h];
  const float den = 2.0f * (uu * uu + 1e-6f);
  float e[8]; float run = 0.f;
  const int base = tid * 8;
#pragma unroll
  for (int j = 0; j < 8; ++j) {
    float d = (float)(base + j);
    e[j] = __expf(-(d * d) / den);
    run += e[j];
  }
  part[tid] = run;
  __syncthreads();
  for (int off = 1; off < 256; off <<= 1) {
    float v = (tid >= off) ? part[tid - off] : 0.f;
    __syncthreads();
    part[tid] += v;
    __syncthreads();
  }
  float c = part[tid] - run;
#pragma unroll
  for (int j = 0; j < 8; ++j) {
    c += e[j];
    Cs[base + j] = c;
    Eb[h * LSEQ + base + j] = e[j];
  }
  __syncthreads();
  const float E0 = Cs[0];
  for (int i = tid; i < LSEQ; i += 256) {
    float s = Cs[i] + Cs[LSEQ - 1 - i] - E0;
    Zb[h * LSEQ + i] = 1.0f / (s + 1e-6f);
  }
}

// ---------------- fused QKV GEMM (pure bf16 MFMA, LDS-free) ------------------
__global__ __launch_bounds__(256) void qkv_gemm(
    const short* __restrict__ xh,
    const short* __restrict__ Bh,
    const float* __restrict__ bq, const float* __restrict__ bk,
    const float* __restrict__ bv,
    short* __restrict__ Qf, short* __restrict__ Kf, short* __restrict__ Vf)
{
  const int tid = threadIdx.x, w = tid >> 6, lane = tid & 63;
  const int l15 = lane & 15, q4 = lane >> 4;
  const int m0 = blockIdx.x * 64, n0 = blockIdx.y * 64;
  const int mrow = m0 + w * 16 + l15;
  f32x4 acc[4] = {{0,0,0,0},{0,0,0,0},{0,0,0,0},{0,0,0,0}};
  for (int k0 = 0; k0 < 256; k0 += 32) {
    bf16x8 ah = *(const bf16x8*)&xh[(size_t)mrow * 256 + k0 + q4 * 8];
#pragma unroll
    for (int nt = 0; nt < 4; ++nt) {
      const size_t bi = (size_t)(n0 + nt * 16 + l15) * 256 + k0 + q4 * 8;
      bf16x8 bh = *(const bf16x8*)&Bh[bi];
      acc[nt] = MFMA(ah, bh, acc[nt], 0, 0, 0);
    }
  }
  const int type = n0 >> 8;        // 0=Q 1=K 2=V
  const int n0l = n0 & 255;
  const float* bias = (type == 0) ? bq : (type == 1) ? bk : bv;
  const float qls = 0.25503489f;   // (1/sqrt(32)) * log2(e)
#pragma unroll
  for (int nt = 0; nt < 4; ++nt) {
    const int col = n0l + nt * 16 + l15;
    const float bvv = bias[col];
    const int hh = col >> 5, dloc = col & 31;
#pragma unroll
    for (int r = 0; r < 4; ++r) {
      const int m = m0 + w * 16 + q4 * 4 + r;
      float v = acc[nt][r] + bvv;
      const int bb = m >> 11, mm = m & 2047, rr = mm & 15;
      if (type == 2) {
        const int kt128 = mm >> 7, low7 = mm & 127;
        const int wv = (low7 >> 4) & 3, ph = low7 >> 6;
        const int c = ph * 16 + rr;
        const size_t idx =
          ((((((size_t)bb * 8 + hh) * 16 + kt128) * 4 + wv) * 2 + (dloc >> 4)) * 64
           + (c >> 3) * 16 + (dloc & 15)) * 8 + (c & 7);
        Vf[idx] = f2bf(v);
      } else if (type == 0) {
        const int qblk = mm >> 5, rg = (mm >> 4) & 1;
        const size_t idx =
          (((((size_t)bb * 8 + hh) * 64 + qblk) * 2 + rg) * 64
           + (dloc >> 3) * 16 + rr) * 8 + (dloc & 7);
        Qf[idx] = f2bf(v * qls);
      } else {
        const int g = mm >> 4;
        const size_t idx =
          ((((size_t)bb * 8 + hh) * 128 + g) * 64
           + (dloc >> 3) * 16 + rr) * 8 + (dloc & 7);
        Kf[idx] = f2bf(v);
      }
    }
  }
}

// ---------------- single-QK^T MFMA flash attention + discrepancy -------------
// v3: pass 1 stores UNNORMALIZED p' = 2^s as bf16 in a 64KB LDS tile (XOR-
// swizzled); pass 2 has NO QK^T MFMA and NO exp — disc = p'*(1/l) via fma,
// PV consumes p' directly (O normalized once in epilogue). Chip-wide this
// halves both the QK MFMAs and the v_exp count vs the 2-pass recompute.
// 512-thr blocks (8 waves k-split one 16-row q-tile), 2048 blocks,
// ~67KB LDS -> 2 blocks/CU = 16 waves/CU.
__global__ __launch_bounds__(512, 4) void attn_kernel(
    const short* __restrict__ Qf, const short* __restrict__ Kf,
    const short* __restrict__ Vf,
    const float* __restrict__ Eb, const float* __restrict__ Zb,
    short* __restrict__ Ohb, short* __restrict__ Olb,
    short* __restrict__ Dp)
{
  __shared__ short Pp[16 * 2048];   // p' tile, XOR-swizzled, c-order columns
  __shared__ float Elds[192];
  __shared__ float lpart[8][16];
  __shared__ float lpn[16];         // 1/l softmax normalizer per q-row
  __shared__ float liz[16];         // prior normalizer per q-row

  const int tid = threadIdx.x, w = tid >> 6, lane = tid & 63;
  const int l15 = lane & 15, q4 = lane >> 4;
  // ---- XCD swizzle: same (b,h) stays on one XCD ----
  const int flat = blockIdx.x + 128 * (blockIdx.y + 8 * blockIdx.z);
  const int slot = flat >> 3;                       // 0..255
  const int g = (flat & 7) | ((slot >> 7) << 3);    // 0..15
  const int h = g & 7, b = g >> 3;
  const int qslot = slot & 127, q0 = qslot * 16;
  const int bh = b * NH + h;

  if (tid < 192) Elds[tid] = Eb[h * LSEQ + tid];
  if (tid < 16)  liz[tid] = Zb[h * LSEQ + q0 + tid];

  const bf16x8* Qf8 = (const bf16x8*)Qf;
  const bf16x8* Kf8 = (const bf16x8*)Kf;
  const bf16x8* Vf8 = (const bf16x8*)Vf;

  bf16x8 qh = Qf8[((size_t)bh * 128 + qslot) * 64 + lane];

  const size_t kfb = (size_t)bh * 128;   // K 16-col-group base
  const size_t vfb = (size_t)bh * 16;    // V kt128 base
  const int wv = w & 3, wh = w >> 2;     // wave -> (16-col slot, 128-chunk parity)

  // ---- phase 1: QK^T, p' = 2^s -> LDS (bf16), row sums ----
  float lac[4] = {0.f, 0.f, 0.f, 0.f};
#pragma unroll 2
  for (int it = 0; it < 8; ++it) {
    const int g16 = it * 16 + wh * 8 + wv;
    bf16x8 k0 = Kf8[(kfb + g16) * 64 + lane];
    bf16x8 k1 = Kf8[(kfb + g16 + 4) * 64 + lane];
    f32x4 s0 = {0.f,0.f,0.f,0.f}; s0 = MFMA(qh, k0, s0, 0, 0, 0);
    f32x4 s1 = {0.f,0.f,0.f,0.f}; s1 = MFMA(qh, k1, s1, 0, 0, 0);
    const int cc0 = it * 256 + w * 32 + l15;   // c-order column for this lane
#pragma unroll
    for (int r = 0; r < 4; ++r) {
      const int row = q4 * 4 + r;
      const int sw = (row & 7) << 3;           // XOR swizzle (shorts)
      float p0 = fexp2(s0[r]);
      float p1 = fexp2(s1[r]);
      lac[r] += p0 + p1;
      Pp[(row * 2048 + cc0) ^ sw]      = bftrunc(p0);
      Pp[(row * 2048 + cc0 + 16) ^ sw] = bftrunc(p1);
    }
  }
#pragma unroll
  for (int r = 0; r < 4; ++r) {
    float v = lac[r];
    v += __shfl_xor(v, 1); v += __shfl_xor(v, 2);
    v += __shfl_xor(v, 4); v += __shfl_xor(v, 8);
    if (l15 == 0) lpart[w][q4 * 4 + r] = v;
  }
  __syncthreads();
  if (tid < 16) {
    float l = 0.f;
#pragma unroll
    for (int w8 = 0; w8 < 8; ++w8) l += lpart[w8][tid];
    lpn[tid] = 1.0f / l;
  }
  __syncthreads();

  float pn4[4], iz4[4];
#pragma unroll
  for (int r = 0; r < 4; ++r) {
    pn4[r] = lpn[q4 * 4 + r];
    iz4[r] = liz[q4 * 4 + r];
  }

  // ---- phase 2: disc (fma only) + PV from LDS p' ----
  const size_t drow = (size_t)(g * 128 + qslot) * LSEQ;
  f32x4 oacc[2] = {{0,0,0,0},{0,0,0,0}};
#pragma unroll 2
  for (int it = 0; it < 8; ++it) {
    const int kt128 = it * 2 + wh;
    bf16x8 vb0 = Vf8[(((vfb + kt128) * 4 + wv) * 2 + 0) * 64 + lane];
    bf16x8 vb1 = Vf8[(((vfb + kt128) * 4 + wv) * 2 + 1) * 64 + lane];
#pragma unroll
    for (int ph = 0; ph < 2; ++ph) {
      const int c0g = kt128 * 128 + ph * 64 + wv * 16;  // global col base
      const int kg = c0g + l15;
      const int dd = c0g - q0;
      const bool near = (dd >= -96) && (dd <= 96);
      const int ccd = it * 256 + w * 32 + ph * 16 + l15;
      float dsum = 0.f;
#pragma unroll
      for (int r = 0; r < 4; ++r) {
        const int row = q4 * 4 + r;
        float p = bf2f(Pp[(row * 2048 + ccd) ^ ((row & 7) << 3)]) * pn4[r];
        if (near) {
          int qrow = q0 + row;
          int dist = (qrow >= kg) ? (qrow - kg) : (kg - qrow);
          dsum += fabsf(p - Elds[dist] * iz4[r]);
        } else {
          dsum += p;   // prior underflows to 0 beyond the near band
        }
      }
      dsum += __shfl_xor(dsum, 16);
      dsum += __shfl_xor(dsum, 32);
      if (q4 == 0) Dp[drow + kg] = f2bf(dsum);   // exactly-once per k
    }
    const int cp = it * 256 + w * 32 + q4 * 8;
    bf16x8 pa = *(const bf16x8*)&Pp[(l15 * 2048 + cp) ^ ((l15 & 7) << 3)];
    oacc[0] = MFMA(pa, vb0, oacc[0], 0, 0, 0);
    oacc[1] = MFMA(pa, vb1, oacc[1], 0, 0, 0);
  }

  // ---- epilogue: 8-wave O reduce, normalize by 1/l, split-bf16 store ----
  __syncthreads();
  float* Ored = (float*)Pp;   // [8][16][17] f32 = 8704B, overlays p'
#pragma unroll
  for (int dt = 0; dt < 2; ++dt) {
#pragma unroll
    for (int r = 0; r < 4; ++r)
      Ored[(w * 16 + q4 * 4 + r) * 17 + l15] = oacc[dt][r];
    __syncthreads();
    if (tid < 256) {
      const int q = tid >> 4, d = tid & 15;
      float v = 0.f;
#pragma unroll
      for (int w8 = 0; w8 < 8; ++w8) v += Ored[(w8 * 16 + q) * 17 + d];
      v *= lpn[q];
      const size_t oo = ((size_t)b * LSEQ + q0 + q) * DMODEL + h * HD + dt * 16 + d;
      short hi = f2bf(v);
      Ohb[oo] = hi;
      Olb[oo] = bftrunc(v - bf2f(hi));
    }
    __syncthreads();
  }
}

// ---------------- tail: output GEMM (512 blocks) + disc reduce (128) ---------
__global__ __launch_bounds__(256) void tail_kernel(
    const short* __restrict__ Ah, const short* __restrict__ Al,
    const short* __restrict__ Bh, const short* __restrict__ Bl,
    const float* __restrict__ bias, float* __restrict__ C,
    const short* __restrict__ Dp, float* __restrict__ disc)
{
  __shared__ float red[8][33];
  const int tid = threadIdx.x;
  if (blockIdx.x < 512) {
    const int w = tid >> 6, lane = tid & 63;
    const int l15 = lane & 15, q4 = lane >> 4;
    const int m0 = (blockIdx.x & 63) * 64, n0 = (blockIdx.x >> 6) * 32;
    const int mrow = m0 + w * 16 + l15;
    f32x4 acc[2] = {{0,0,0,0},{0,0,0,0}};
    for (int k0 = 0; k0 < 256; k0 += 32) {
      bf16x8 ah = *(const bf16x8*)&Ah[(size_t)mrow * 256 + k0 + q4 * 8];
      bf16x8 al = *(const bf16x8*)&Al[(size_t)mrow * 256 + k0 + q4 * 8];
#pragma unroll
      for (int nt = 0; nt < 2; ++nt) {
        const size_t bi = (size_t)(n0 + nt * 16 + l15) * 256 + k0 + q4 * 8;
        bf16x8 bh = *(const bf16x8*)&Bh[bi];
        bf16x8 bl = *(const bf16x8*)&Bl[bi];
        acc[nt] = MFMA(ah, bh, acc[nt], 0, 0, 0);
        acc[nt] = MFMA(al, bh, acc[nt], 0, 0, 0);
        acc[nt] = MFMA(ah, bl, acc[nt], 0, 0, 0);
      }
    }
#pragma unroll
    for (int nt = 0; nt < 2; ++nt) {
      const int col = n0 + nt * 16 + l15;
      const float bvv = bias[col];
#pragma unroll
      for (int r = 0; r < 4; ++r) {
        const int m = m0 + w * 16 + q4 * 4 + r;
        C[(size_t)m * 256 + col] = acc[nt][r] + bvv;
      }
    }
    return;
  }
  // ---- disc reduce: sum 1024 bf16 partial rows per batch ----
  const int bid = blockIdx.x - 512;
  const int b = bid >> 6, kb = (bid & 63) * 32;
  const int k = kb + (tid & 31), sg = tid >> 5;
  float acc = 0.f;
  const short* base = Dp + ((size_t)b * 1024 + (size_t)sg * 128) * LSEQ + k;
#pragma unroll 4
  for (int i = 0; i < 128; ++i) acc += bf2f(base[(size_t)i * LSEQ]);
  red[sg][tid & 31] = acc;
  __syncthreads();
  if (tid < 32) {
    float v = 0.f;
#pragma unroll
    for (int s2 = 0; s2 < 8; ++s2) v += red[s2][tid];
    disc[b * LSEQ + kb + tid] = v * (1.0f / ((float)NH * (float)LSEQ));
  }
}

extern "C" void kernel_launch(void* const* d_in, const int* in_sizes, int n_in,
                              void* d_out, int out_size, void* d_ws, size_t ws_size,
                              hipStream_t stream)
{
  const float* x  = (const float*)d_in[0];
  const float* Wq = (const float*)d_in[1];
  const float* bq = (const float*)d_in[2];
  const float* Wk = (const float*)d_in[3];
  const float* bk = (const float*)d_in[4];
  const float* Wv = (const float*)d_in[5];
  const float* bv = (const float*)d_in[6];
  const float* u  = (const float*)d_in[7];
  const float* Wo = (const float*)d_in[8];
  const float* bo = (const float*)d_in[9];

  float* out  = (float*)d_out;
  float* disc = out + (size_t)2 * LSEQ * DMODEL;

  char* w8 = (char*)d_ws;
  const size_t MB = 1u << 20;
  short* Qfb = (short*)(w8);               // 2MB each
  short* Kfb = (short*)(w8 + 2 * MB);
  short* Vfb = (short*)(w8 + 4 * MB);
  short* Ohb = (short*)(w8 + 6 * MB);
  short* Olb = (short*)(w8 + 8 * MB);
  short* Wh  = (short*)(w8 + 10 * MB);                 // 384KB (Wqkv bf16)
  short* Woh = (short*)(w8 + 10 * MB + 393216);        // 128KB
  short* Wol = (short*)(w8 + 10 * MB + 524288);        // 128KB
  float* Eb  = (float*)(w8 + 11 * MB);                 // 64KB
  float* Zb  = (float*)(w8 + 11 * MB + 65536);         // 64KB
  short* xh  = (short*)(w8 + 12 * MB);                 // 2MB (x bf16)
  short* Dp  = (short*)(w8 + 14 * MB);                 // 8MB disc partials [2048][2048] bf16

  aux_kernel<<<1288, 256, 0, stream>>>(x, Wq, Wk, Wv, Wo, u, xh, Wh, Woh, Wol, Eb, Zb);
  qkv_gemm<<<dim3(64, 12), 256, 0, stream>>>(xh, Wh, bq, bk, bv, Qfb, Kfb, Vfb);
  attn_kernel<<<dim3(128, 8, 2), 512, 0, stream>>>(Qfb, Kfb, Vfb, Eb, Zb,
                                                   Ohb, Olb, Dp);
  tail_kernel<<<640, 256, 0, stream>>>(Ohb, Olb, Woh, Wol, bo, out, Dp, disc);
}

// Round 4
// 159.910 us; speedup vs baseline: 1.0344x; 1.0344x over previous
//
#include <hip/hip_runtime.h>
#include <hip/hip_bf16.h>
#include <math.h>

#define LSEQ 2048
#define DMODEL 256
#define NH 8
#define HD 32

typedef __attribute__((ext_vector_type(8))) short bf16x8;
typedef __attribute__((ext_vector_type(4))) float f32x4;

#define MFMA __builtin_amdgcn_mfma_f32_16x16x32_bf16

__device__ __forceinline__ short f2bf(float x) {
  __hip_bfloat16 h = __float2bfloat16(x);
  return __builtin_bit_cast(short, h);
}
__device__ __forceinline__ float bf2f(short s) {
  __hip_bfloat16 h = __builtin_bit_cast(__hip_bfloat16, s);
  return __bfloat162float(h);
}
__device__ __forceinline__ short bftrunc(float x) {      // truncating f32->bf16
  return (short)(__builtin_bit_cast(unsigned int, x) >> 16);
}
// bare v_exp_f32 (2^x) — skip OCML denormal fixup (underflowed p contribute 0)
__device__ __forceinline__ float fexp2(float x) {
#if __has_builtin(__builtin_amdgcn_exp2f)
  return __builtin_amdgcn_exp2f(x);
#else
  return __expf(x * 0.6931471805599453f);
#endif
}

// ---- aux: x -> bf16, Wqkv -> bf16, Wo -> split bf16, prior tables ----
__global__ __launch_bounds__(256) void aux_kernel(
    const float* __restrict__ x,
    const float* __restrict__ Wq, const float* __restrict__ Wk,
    const float* __restrict__ Wv, const float* __restrict__ Wo,
    const float* __restrict__ u,
    short* __restrict__ xh,
    short* __restrict__ Wh,
    short* __restrict__ Woh, short* __restrict__ Wol,
    float* __restrict__ Eb, float* __restrict__ Zb)
{
  __shared__ float Cs[LSEQ];
  __shared__ float part[256];
  const int tid = threadIdx.x;
  if (blockIdx.x < 1024) {            // x (4096x256 fp32) -> bf16, RNE
    const int i4 = (blockIdx.x * 256 + tid) * 4;
    float4 v = *(const float4*)(x + i4);
    *(short4*)(xh + i4) = make_short4(f2bf(v.x), f2bf(v.y), f2bf(v.z), f2bf(v.w));
    return;
  }
  const int bx = blockIdx.x - 1024;
  if (bx < 256) {
    const int i4 = (bx * 256 + tid) * 4;
    if (i4 < 196608) {
      int row = i4 >> 8, col = i4 & 255;
      const float* W = (row < 256) ? Wq : (row < 512) ? Wk : Wv;
      float4 v = *(const float4*)(W + (row & 255) * 256 + col);
      *(short4*)(Wh + i4) = make_short4(f2bf(v.x), f2bf(v.y), f2bf(v.z), f2bf(v.w));
    } else {
      int j = i4 - 196608;
      float4 v = *(const float4*)(Wo + j);
      short h0 = f2bf(v.x), h1 = f2bf(v.y), h2 = f2bf(v.z), h3 = f2bf(v.w);
      *(short4*)(Woh + j) = make_short4(h0, h1, h2, h3);
      *(short4*)(Wol + j) = make_short4(bftrunc(v.x - bf2f(h0)), bftrunc(v.y - bf2f(h1)),
                                        bftrunc(v.z - bf2f(h2)), bftrunc(v.w - bf2f(h3)));
    }
    return;
  }
  const int h = bx - 256;
  const float uu = u[h];
  const float den = 2.0f * (uu * uu + 1e-6f);
  float e[8]; float run = 0.f;
  const int base = tid * 8;
#pragma unroll
  for (int j = 0; j < 8; ++j) {
    float d = (float)(base + j);
    e[j] = __expf(-(d * d) / den);
    run += e[j];
  }
  part[tid] = run;
  __syncthreads();
  for (int off = 1; off < 256; off <<= 1) {
    float v = (tid >= off) ? part[tid - off] : 0.f;
    __syncthreads();
    part[tid] += v;
    __syncthreads();
  }
  float c = part[tid] - run;
#pragma unroll
  for (int j = 0; j < 8; ++j) {
    c += e[j];
    Cs[base + j] = c;
    Eb[h * LSEQ + base + j] = e[j];
  }
  __syncthreads();
  const float E0 = Cs[0];
  for (int i = tid; i < LSEQ; i += 256) {
    float s = Cs[i] + Cs[LSEQ - 1 - i] - E0;
    Zb[h * LSEQ + i] = 1.0f / (s + 1e-6f);
  }
}

// ---------------- fused QKV GEMM (pure bf16 MFMA, LDS-free) ------------------
__global__ __launch_bounds__(256) void qkv_gemm(
    const short* __restrict__ xh,
    const short* __restrict__ Bh,
    const float* __restrict__ bq, const float* __restrict__ bk,
    const float* __restrict__ bv,
    short* __restrict__ Qf, short* __restrict__ Kf, short* __restrict__ Vf)
{
  const int tid = threadIdx.x, w = tid >> 6, lane = tid & 63;
  const int l15 = lane & 15, q4 = lane >> 4;
  const int m0 = blockIdx.x * 64, n0 = blockIdx.y * 64;
  const int mrow = m0 + w * 16 + l15;
  f32x4 acc[4] = {{0,0,0,0},{0,0,0,0},{0,0,0,0},{0,0,0,0}};
  for (int k0 = 0; k0 < 256; k0 += 32) {
    bf16x8 ah = *(const bf16x8*)&xh[(size_t)mrow * 256 + k0 + q4 * 8];
#pragma unroll
    for (int nt = 0; nt < 4; ++nt) {
      const size_t bi = (size_t)(n0 + nt * 16 + l15) * 256 + k0 + q4 * 8;
      bf16x8 bh = *(const bf16x8*)&Bh[bi];
      acc[nt] = MFMA(ah, bh, acc[nt], 0, 0, 0);
    }
  }
  const int type = n0 >> 8;        // 0=Q 1=K 2=V
  const int n0l = n0 & 255;
  const float* bias = (type == 0) ? bq : (type == 1) ? bk : bv;
  const float qls = 0.25503489f;   // (1/sqrt(32)) * log2(e)
#pragma unroll
  for (int nt = 0; nt < 4; ++nt) {
    const int col = n0l + nt * 16 + l15;
    const float bvv = bias[col];
    const int hh = col >> 5, dloc = col & 31;
#pragma unroll
    for (int r = 0; r < 4; ++r) {
      const int m = m0 + w * 16 + q4 * 4 + r;
      float v = acc[nt][r] + bvv;
      const int bb = m >> 11, mm = m & 2047, rr = mm & 15;
      if (type == 2) {
        const int kt128 = mm >> 7, low7 = mm & 127;
        const int wv = (low7 >> 4) & 3, ph = low7 >> 6;
        const int c = ph * 16 + rr;
        const size_t idx =
          ((((((size_t)bb * 8 + hh) * 16 + kt128) * 4 + wv) * 2 + (dloc >> 4)) * 64
           + (c >> 3) * 16 + (dloc & 15)) * 8 + (c & 7);
        Vf[idx] = f2bf(v);
      } else if (type == 0) {
        const int qblk = mm >> 5, rg = (mm >> 4) & 1;
        const size_t idx =
          (((((size_t)bb * 8 + hh) * 64 + qblk) * 2 + rg) * 64
           + (dloc >> 3) * 16 + rr) * 8 + (dloc & 7);
        Qf[idx] = f2bf(v * qls);
      } else {
        const int g = mm >> 4;
        const size_t idx =
          ((((size_t)bb * 8 + hh) * 128 + g) * 64
           + (dloc >> 3) * 16 + rr) * 8 + (dloc & 7);
        Kf[idx] = f2bf(v);
      }
    }
  }
}

// ---------------- one-pass MFMA flash attention + deferred disc --------------
// v4: single QK^T pass. Per 32-col chunk: MFMA -> exp2 -> bf16 (RNE) -> (a) 8
// b16 stores into the wave-PRIVATE 1.25KB Pt tile -> ds_read_b128 -> PV MFMA
// immediately (PV needs no normalizer: O scaled by 1/l in epilogue), and (b)
// the same bf16 values packed into 32 VGPRs (pc[8][4], fully static indexing).
// After the l-reduce, disc runs entirely from registers: unpack = 1 shift,
// fma with 1/l, cheap r2-orientation column reduce (2 shfl per 16 cols).
// No big LDS tile, no scalar LDS reads, no XOR math, no QK^T recompute.
__global__ __launch_bounds__(512, 4) void attn_kernel(
    const short* __restrict__ Qf, const short* __restrict__ Kf,
    const short* __restrict__ Vf,
    const float* __restrict__ Eb, const float* __restrict__ Zb,
    short* __restrict__ Ohb, short* __restrict__ Olb,
    short* __restrict__ Dp)
{
  __shared__ short Pt[8][16][40];   // wave-private P chunk (reused as Ored)
  __shared__ float Elds[192];
  __shared__ float lpart[8][16];
  __shared__ float lpn[16];         // 1/l per q-row
  __shared__ float liz[16];         // prior normalizer per q-row

  const int tid = threadIdx.x, w = tid >> 6, lane = tid & 63;
  const int l15 = lane & 15, q4 = lane >> 4;
  // ---- XCD swizzle: same (b,h) stays on one XCD ----
  const int flat = blockIdx.x + 128 * (blockIdx.y + 8 * blockIdx.z);
  const int slot = flat >> 3;                       // 0..255
  const int g = (flat & 7) | ((slot >> 7) << 3);    // 0..15
  const int h = g & 7, b = g >> 3;
  const int qslot = slot & 127, q0 = qslot * 16;
  const int bh = b * NH + h;

  if (tid < 192) Elds[tid] = Eb[h * LSEQ + tid];
  if (tid < 16)  liz[tid] = Zb[h * LSEQ + q0 + tid];

  const bf16x8* Qf8 = (const bf16x8*)Qf;
  const bf16x8* Kf8 = (const bf16x8*)Kf;
  const bf16x8* Vf8 = (const bf16x8*)Vf;

  bf16x8 qh = Qf8[((size_t)bh * 128 + qslot) * 64 + lane];

  const size_t kfb = (size_t)bh * 128;   // K 16-col-group base
  const size_t vfb = (size_t)bh * 16;    // V kt128 base
  const int wv = w & 3, wh = w >> 2;     // wave -> (16-col slot, 128-chunk parity)

  unsigned int pc[8][4];                 // packed bf16 p' cache (static idx only)
  float lac[4] = {0.f, 0.f, 0.f, 0.f};
  f32x4 oacc[2] = {{0,0,0,0},{0,0,0,0}};

  // ---- single pass: QK^T -> p' -> {reg cache, wave-private LDS} -> PV ----
#pragma unroll
  for (int it = 0; it < 8; ++it) {
    const int g16 = it * 16 + wh * 8 + wv;
    bf16x8 k0 = Kf8[(kfb + g16) * 64 + lane];
    bf16x8 k1 = Kf8[(kfb + g16 + 4) * 64 + lane];
    const int kt128 = it * 2 + wh;
    bf16x8 vb0 = Vf8[(((vfb + kt128) * 4 + wv) * 2 + 0) * 64 + lane];
    bf16x8 vb1 = Vf8[(((vfb + kt128) * 4 + wv) * 2 + 1) * 64 + lane];
    f32x4 s0 = {0.f,0.f,0.f,0.f}; s0 = MFMA(qh, k0, s0, 0, 0, 0);
    f32x4 s1 = {0.f,0.f,0.f,0.f}; s1 = MFMA(qh, k1, s1, 0, 0, 0);
    short c0[4], c1[4];
#pragma unroll
    for (int r = 0; r < 4; ++r) {
      float p0 = fexp2(s0[r]);
      float p1 = fexp2(s1[r]);
      lac[r] += p0 + p1;
      c0[r] = f2bf(p0);
      c1[r] = f2bf(p1);
      Pt[w][q4 * 4 + r][l15]      = c0[r];
      Pt[w][q4 * 4 + r][16 + l15] = c1[r];
    }
    pc[it][0] = (unsigned int)(unsigned short)c0[0] | ((unsigned int)(unsigned short)c0[1] << 16);
    pc[it][1] = (unsigned int)(unsigned short)c0[2] | ((unsigned int)(unsigned short)c0[3] << 16);
    pc[it][2] = (unsigned int)(unsigned short)c1[0] | ((unsigned int)(unsigned short)c1[1] << 16);
    pc[it][3] = (unsigned int)(unsigned short)c1[2] | ((unsigned int)(unsigned short)c1[3] << 16);
    // wave-private: compiler inserts the lgkmcnt wait; wave-synchronous lanes
    // make the cross-lane write->read safe without a barrier (r2-proven).
    bf16x8 pa = *(const bf16x8*)&Pt[w][l15][q4 * 8];
    oacc[0] = MFMA(pa, vb0, oacc[0], 0, 0, 0);
    oacc[1] = MFMA(pa, vb1, oacc[1], 0, 0, 0);
  }

  // ---- l-reduce across 16 lanes then 8 waves ----
#pragma unroll
  for (int r = 0; r < 4; ++r) {
    float v = lac[r];
    v += __shfl_xor(v, 1); v += __shfl_xor(v, 2);
    v += __shfl_xor(v, 4); v += __shfl_xor(v, 8);
    if (l15 == 0) lpart[w][q4 * 4 + r] = v;
  }
  __syncthreads();
  if (tid < 16) {
    float l = 0.f;
#pragma unroll
    for (int w8 = 0; w8 < 8; ++w8) l += lpart[w8][tid];
    lpn[tid] = 1.0f / l;
  }
  __syncthreads();

  float pn4[4], iz4[4];
#pragma unroll
  for (int r = 0; r < 4; ++r) {
    pn4[r] = lpn[q4 * 4 + r];
    iz4[r] = liz[q4 * 4 + r];
  }
  const int qrow0 = q0 + q4 * 4;

  // ---- deferred disc: entirely from the register cache ----
  const size_t drow = (size_t)(g * 128 + qslot) * LSEQ;
#pragma unroll
  for (int it = 0; it < 8; ++it) {
#pragma unroll
    for (int ph = 0; ph < 2; ++ph) {
      const int c0g = (it * 2 + wh) * 128 + ph * 64 + wv * 16;
      const int kg = c0g + l15;
      const int dd = c0g - q0;
      const bool near = (dd >= -96) && (dd <= 96);
      const unsigned int wlo = pc[it][ph * 2 + 0];
      const unsigned int whi = pc[it][ph * 2 + 1];
      float pr[4];
      pr[0] = __builtin_bit_cast(float, wlo << 16);
      pr[1] = __builtin_bit_cast(float, wlo & 0xffff0000u);
      pr[2] = __builtin_bit_cast(float, whi << 16);
      pr[3] = __builtin_bit_cast(float, whi & 0xffff0000u);
      float dsum = 0.f;
      if (near) {
#pragma unroll
        for (int r = 0; r < 4; ++r) {
          float p = pr[r] * pn4[r];
          int qrow = qrow0 + r;
          int dist = (qrow >= kg) ? (qrow - kg) : (kg - qrow);
          dsum += fabsf(p - Elds[dist] * iz4[r]);
        }
      } else {
        dsum = pr[0] * pn4[0] + pr[1] * pn4[1] + pr[2] * pn4[2] + pr[3] * pn4[3];
      }
      dsum += __shfl_xor(dsum, 16);
      dsum += __shfl_xor(dsum, 32);
      if (q4 == 0) Dp[drow + kg] = f2bf(dsum);   // exactly-once per k
    }
  }

  // ---- epilogue: 8-wave O reduce, normalize by 1/l, split-bf16 store ----
  __syncthreads();
  float* Ored = (float*)Pt;   // [8][16][17] f32 = 8704B <= 10240B
#pragma unroll
  for (int dt = 0; dt < 2; ++dt) {
#pragma unroll
    for (int r = 0; r < 4; ++r)
      Ored[(w * 16 + q4 * 4 + r) * 17 + l15] = oacc[dt][r];
    __syncthreads();
    if (tid < 256) {
      const int q = tid >> 4, d = tid & 15;
      float v = 0.f;
#pragma unroll
      for (int w8 = 0; w8 < 8; ++w8) v += Ored[(w8 * 16 + q) * 17 + d];
      v *= lpn[q];
      const size_t oo = ((size_t)b * LSEQ + q0 + q) * DMODEL + h * HD + dt * 16 + d;
      short hi = f2bf(v);
      Ohb[oo] = hi;
      Olb[oo] = bftrunc(v - bf2f(hi));
    }
    __syncthreads();
  }
}

// ---------------- tail: output GEMM (512 blocks) + disc reduce (128) ---------
__global__ __launch_bounds__(256) void tail_kernel(
    const short* __restrict__ Ah, const short* __restrict__ Al,
    const short* __restrict__ Bh, const short* __restrict__ Bl,
    const float* __restrict__ bias, float* __restrict__ C,
    const short* __restrict__ Dp, float* __restrict__ disc)
{
  __shared__ float red[8][33];
  const int tid = threadIdx.x;
  if (blockIdx.x < 512) {
    const int w = tid >> 6, lane = tid & 63;
    const int l15 = lane & 15, q4 = lane >> 4;
    const int m0 = (blockIdx.x & 63) * 64, n0 = (blockIdx.x >> 6) * 32;
    const int mrow = m0 + w * 16 + l15;
    f32x4 acc[2] = {{0,0,0,0},{0,0,0,0}};
    for (int k0 = 0; k0 < 256; k0 += 32) {
      bf16x8 ah = *(const bf16x8*)&Ah[(size_t)mrow * 256 + k0 + q4 * 8];
      bf16x8 al = *(const bf16x8*)&Al[(size_t)mrow * 256 + k0 + q4 * 8];
#pragma unroll
      for (int nt = 0; nt < 2; ++nt) {
        const size_t bi = (size_t)(n0 + nt * 16 + l15) * 256 + k0 + q4 * 8;
        bf16x8 bh = *(const bf16x8*)&Bh[bi];
        bf16x8 bl = *(const bf16x8*)&Bl[bi];
        acc[nt] = MFMA(ah, bh, acc[nt], 0, 0, 0);
        acc[nt] = MFMA(al, bh, acc[nt], 0, 0, 0);
        acc[nt] = MFMA(ah, bl, acc[nt], 0, 0, 0);
      }
    }
#pragma unroll
    for (int nt = 0; nt < 2; ++nt) {
      const int col = n0 + nt * 16 + l15;
      const float bvv = bias[col];
#pragma unroll
      for (int r = 0; r < 4; ++r) {
        const int m = m0 + w * 16 + q4 * 4 + r;
        C[(size_t)m * 256 + col] = acc[nt][r] + bvv;
      }
    }
    return;
  }
  // ---- disc reduce: sum 1024 bf16 partial rows per batch ----
  const int bid = blockIdx.x - 512;
  const int b = bid >> 6, kb = (bid & 63) * 32;
  const int k = kb + (tid & 31), sg = tid >> 5;
  float acc = 0.f;
  const short* base = Dp + ((size_t)b * 1024 + (size_t)sg * 128) * LSEQ + k;
#pragma unroll 4
  for (int i = 0; i < 128; ++i) acc += bf2f(base[(size_t)i * LSEQ]);
  red[sg][tid & 31] = acc;
  __syncthreads();
  if (tid < 32) {
    float v = 0.f;
#pragma unroll
    for (int s2 = 0; s2 < 8; ++s2) v += red[s2][tid];
    disc[b * LSEQ + kb + tid] = v * (1.0f / ((float)NH * (float)LSEQ));
  }
}

extern "C" void kernel_launch(void* const* d_in, const int* in_sizes, int n_in,
                              void* d_out, int out_size, void* d_ws, size_t ws_size,
                              hipStream_t stream)
{
  const float* x  = (const float*)d_in[0];
  const float* Wq = (const float*)d_in[1];
  const float* bq = (const float*)d_in[2];
  const float* Wk = (const float*)d_in[3];
  const float* bk = (const float*)d_in[4];
  const float* Wv = (const float*)d_in[5];
  const float* bv = (const float*)d_in[6];
  const float* u  = (const float*)d_in[7];
  const float* Wo = (const float*)d_in[8];
  const float* bo = (const float*)d_in[9];

  float* out  = (float*)d_out;
  float* disc = out + (size_t)2 * LSEQ * DMODEL;

  char* w8 = (char*)d_ws;
  const size_t MB = 1u << 20;
  short* Qfb = (short*)(w8);               // 2MB each
  short* Kfb = (short*)(w8 + 2 * MB);
  short* Vfb = (short*)(w8 + 4 * MB);
  short* Ohb = (short*)(w8 + 6 * MB);
  short* Olb = (short*)(w8 + 8 * MB);
  short* Wh  = (short*)(w8 + 10 * MB);                 // 384KB (Wqkv bf16)
  short* Woh = (short*)(w8 + 10 * MB + 393216);        // 128KB
  short* Wol = (short*)(w8 + 10 * MB + 524288);        // 128KB
  float* Eb  = (float*)(w8 + 11 * MB);                 // 64KB
  float* Zb  = (float*)(w8 + 11 * MB + 65536);         // 64KB
  short* xh  = (short*)(w8 + 12 * MB);                 // 2MB (x bf16)
  short* Dp  = (short*)(w8 + 14 * MB);                 // 8MB disc partials [2048][2048] bf16

  aux_kernel<<<1288, 256, 0, stream>>>(x, Wq, Wk, Wv, Wo, u, xh, Wh, Woh, Wol, Eb, Zb);
  qkv_gemm<<<dim3(64, 12), 256, 0, stream>>>(xh, Wh, bq, bk, bv, Qfb, Kfb, Vfb);
  attn_kernel<<<dim3(128, 8, 2), 512, 0, stream>>>(Qfb, Kfb, Vfb, Eb, Zb,
                                                   Ohb, Olb, Dp);
  tail_kernel<<<640, 256, 0, stream>>>(Ohb, Olb, Woh, Wol, bo, out, Dp, disc);
}